// Round 4
// baseline (208.644 us; speedup 1.0000x reference)
//
#include <hip/hip_runtime.h>

#define IN_F 4096
#define OUT_F 4096
#define NTOK 8192   // B*S = 4*2048
#define KDIM 4096

using i32x4 = __attribute__((ext_vector_type(4))) int;
using f32x4 = __attribute__((ext_vector_type(4))) float;

__device__ __forceinline__ void gload_lds16(const void* g, void* l) {
  __builtin_amdgcn_global_load_lds(
      (const __attribute__((address_space(1))) void*)g,
      (__attribute__((address_space(3))) void*)l, 16, 0, 0);
}

#define WAITV(n) asm volatile("s_waitcnt vmcnt(" #n ")" ::: "memory")
#define BAR() do { asm volatile("" ::: "memory"); __builtin_amdgcn_s_barrier(); \
                   asm volatile("" ::: "memory"); } while (0)

// ---------------- Pass 1: RMSNorm + per-token int8 absmax quant ------------
__global__ __launch_bounds__(256) void rmsq_kernel(
    const float* __restrict__ x, const float* __restrict__ rmsw,
    signed char* __restrict__ q, float* __restrict__ dscale) {
  const int tok = blockIdx.x;
  const int tid = threadIdx.x;
  const f32x4* xr = (const f32x4*)(x + (size_t)tok * IN_F);
  const f32x4* wr = (const f32x4*)rmsw;

  f32x4 v[4];
  float ss = 0.f;
#pragma unroll
  for (int c = 0; c < 4; ++c) {
    v[c] = xr[c * 256 + tid];
    ss += v[c].x * v[c].x + v[c].y * v[c].y + v[c].z * v[c].z + v[c].w * v[c].w;
  }

  __shared__ float red[4];
#pragma unroll
  for (int off = 32; off > 0; off >>= 1) ss += __shfl_down(ss, off, 64);
  const int wid = tid >> 6;
  if ((tid & 63) == 0) red[wid] = ss;
  __syncthreads();
  const float tot = red[0] + red[1] + red[2] + red[3];
  const float rinv = rsqrtf(tot * (1.0f / IN_F) + 1e-6f);

  f32x4 h[4];
  float amax = 0.f;
#pragma unroll
  for (int c = 0; c < 4; ++c) {
    f32x4 w = wr[c * 256 + tid];
    h[c].x = v[c].x * rinv * w.x;
    h[c].y = v[c].y * rinv * w.y;
    h[c].z = v[c].z * rinv * w.z;
    h[c].w = v[c].w * rinv * w.w;
    amax = fmaxf(amax, fabsf(h[c].x));
    amax = fmaxf(amax, fabsf(h[c].y));
    amax = fmaxf(amax, fabsf(h[c].z));
    amax = fmaxf(amax, fabsf(h[c].w));
  }

  __syncthreads();
#pragma unroll
  for (int off = 32; off > 0; off >>= 1)
    amax = fmaxf(amax, __shfl_down(amax, off, 64));
  if ((tid & 63) == 0) red[wid] = amax;
  __syncthreads();
  amax = fmaxf(fmaxf(red[0], red[1]), fmaxf(red[2], red[3]));
  amax = fmaxf(amax, 1e-5f);
  const float qs = 127.0f / amax;
  if (tid == 0) dscale[tok] = amax * (1.0f / 127.0f);

  uint* qo = (uint*)(q + (size_t)tok * IN_F);
#pragma unroll
  for (int c = 0; c < 4; ++c) {
    float r0 = fminf(fmaxf(rintf(h[c].x * qs), -128.f), 127.f);
    float r1 = fminf(fmaxf(rintf(h[c].y * qs), -128.f), 127.f);
    float r2 = fminf(fmaxf(rintf(h[c].z * qs), -128.f), 127.f);
    float r3 = fminf(fmaxf(rintf(h[c].w * qs), -128.f), 127.f);
    uint p = ((uint)((int)r0 & 255)) | ((uint)((int)r1 & 255) << 8) |
             ((uint)((int)r2 & 255) << 16) | ((uint)((int)r3 & 255) << 24);
    qo[c * 256 + tid] = p;
  }
}

// ---------------- Pass 2: W float32 {-1,0,1} -> int8 ----------------------
__global__ __launch_bounds__(256) void wconv_kernel(
    const float* __restrict__ W, signed char* __restrict__ Wq) {
  const int idx = blockIdx.x * 256 + threadIdx.x;
  f32x4 w = ((const f32x4*)W)[idx];
  uint p = ((uint)((int)w.x & 255)) | ((uint)((int)w.y & 255) << 8) |
           ((uint)((int)w.z & 255) << 16) | ((uint)((int)w.w & 255) << 24);
  ((uint*)Wq)[idx] = p;
}

// ---------------- Pass 3: 4-phase deep-pipelined int8 GEMM -----------------
// 256x256 tile, BK=64, 8 waves (2Mx4N). 4 quadrant-phases per K-tile:
// {6 ds_read | 1 stage chunk | barrier | setprio 8xMFMA | barrier},
// counted vmcnt once per K-tile (never 0 mid-loop), 4 LDS buffers (depth-3).
#define BM 256
#define BN 256
#define BK 64
#define NT (KDIM / BK)      // 64 K-tiles
#define TILEB (BM * BK)     // 16 KB (one A or B tile)
#define BUFB (2 * TILEB)    // 32 KB per buffer (A + B)
#define NBUF 4

__global__ __launch_bounds__(512, 2) void gemm_kernel(
    const signed char* __restrict__ A, const signed char* __restrict__ Bw,
    const float* __restrict__ dscale, const float* __restrict__ bias,
    const float* __restrict__ wscale_p, float* __restrict__ out) {
  __shared__ __align__(16) signed char lds[NBUF * BUFB];  // 128 KB

  const int tid = threadIdx.x;
  const int lane = tid & 63;
  const int wid = tid >> 6;
  const int wr = wid >> 2;  // 0..1 : 128 output rows
  const int wc = wid & 3;   // 0..3 : 64 output cols

  // XCD-aware bijective swizzle (512 blocks, 512%8==0)
  const int bid = blockIdx.x;
  const int swz = (bid & 7) * 64 + (bid >> 3);
  const int m0 = (swz & 31) * BM;
  const int n0 = (swz >> 5) * BN;

  // staging: chunk c -> row r=c>>2, physical slot p=c&3 holds logical slot
  // s = p ^ ((r>>1)&3)  (pre-swizzled global source, linear LDS dest)
  const int cA0 = tid, cA1 = tid + 512;
  const int rA0 = cA0 >> 2, rA1 = cA1 >> 2;
  const int sA0 = (cA0 & 3) ^ ((rA0 >> 1) & 3);
  const int sA1 = (cA1 & 3) ^ ((rA1 >> 1) & 3);
  const signed char* agp0 = A + (size_t)(m0 + rA0) * KDIM + sA0 * 16;
  const signed char* agp1 = A + (size_t)(m0 + rA1) * KDIM + sA1 * 16;
  const signed char* bgp0 = Bw + (size_t)(n0 + rA0) * KDIM + sA0 * 16;
  const signed char* bgp1 = Bw + (size_t)(n0 + rA1) * KDIM + sA1 * 16;

#define STAGE_ALL(kt, bufoff)                                              \
  do {                                                                     \
    const int k0_ = (kt) * BK;                                             \
    signed char* lb_ = &lds[(bufoff)];                                     \
    gload_lds16(agp0 + k0_, lb_ + cA0 * 16);                               \
    gload_lds16(agp1 + k0_, lb_ + cA1 * 16);                               \
    gload_lds16(bgp0 + k0_, lb_ + TILEB + cA0 * 16);                       \
    gload_lds16(bgp1 + k0_, lb_ + TILEB + cA1 * 16);                       \
  } while (0)

  // fragment read offsets (swizzled, loop-invariant)
  const int fr = lane & 15;
  const int ks = lane >> 4;
  int offA[8], offB[4];
#pragma unroll
  for (int mi = 0; mi < 8; ++mi) {
    const int row = wr * 128 + mi * 16 + fr;
    offA[mi] = row * BK + ((ks ^ ((row >> 1) & 3)) * 16);
  }
#pragma unroll
  for (int ni = 0; ni < 4; ++ni) {
    const int row = wc * 64 + ni * 16 + fr;
    offB[ni] = TILEB + row * BK + ((ks ^ ((row >> 1) & 3)) * 16);
  }

  i32x4 acc[8][4];
#pragma unroll
  for (int i = 0; i < 8; ++i)
#pragma unroll
    for (int j = 0; j < 4; ++j) acc[i][j] = (i32x4){0, 0, 0, 0};

  // prologue: fill depth-3 pipeline, then GUARD TILE 0 (the Round-3 bug):
  // 12 outstanding; WAITV(8) drains the 4 oldest = tile 0's chunks; BAR makes
  // every wave's chunks visible before any wave reads tile 0.
  STAGE_ALL(0, 0);
  STAGE_ALL(1, BUFB);
  STAGE_ALL(2, 2 * BUFB);
  WAITV(8);
  BAR();

  int bufo = 0;           // buffer being read (tile t)
  int sbufo = 3 * BUFB;   // buffer being staged (tile t+3)
  for (int t = 0; t < NT; ++t) {
    const signed char* bp = &lds[bufo];
    signed char* sb = &lds[sbufo];
    const int k3 = (t + 3) * BK;
    const bool more = (t + 3 < NT);

#pragma unroll
    for (int q = 0; q < 4; ++q) {
      const int mi0 = (q >> 1) * 4;
      const int ni0 = (q & 1) * 2;

      // ds_read this quadrant's fragments
      i32x4 af0 = *(const i32x4*)(bp + offA[mi0 + 0]);
      i32x4 af1 = *(const i32x4*)(bp + offA[mi0 + 1]);
      i32x4 af2 = *(const i32x4*)(bp + offA[mi0 + 2]);
      i32x4 af3 = *(const i32x4*)(bp + offA[mi0 + 3]);
      i32x4 bf0 = *(const i32x4*)(bp + offB[ni0 + 0]);
      i32x4 bf1 = *(const i32x4*)(bp + offB[ni0 + 1]);

      // issue one staging chunk of tile t+3
      if (more) {
        if (q == 0)      gload_lds16(agp0 + k3, sb + cA0 * 16);
        else if (q == 1) gload_lds16(agp1 + k3, sb + cA1 * 16);
        else if (q == 2) gload_lds16(bgp0 + k3, sb + TILEB + cA0 * 16);
        else             gload_lds16(bgp1 + k3, sb + TILEB + cA1 * 16);
      }

      BAR();
      __builtin_amdgcn_s_setprio(1);
      acc[mi0 + 0][ni0 + 0] = __builtin_amdgcn_mfma_i32_16x16x64_i8(af0, bf0, acc[mi0 + 0][ni0 + 0], 0, 0, 0);
      acc[mi0 + 1][ni0 + 0] = __builtin_amdgcn_mfma_i32_16x16x64_i8(af1, bf0, acc[mi0 + 1][ni0 + 0], 0, 0, 0);
      acc[mi0 + 2][ni0 + 0] = __builtin_amdgcn_mfma_i32_16x16x64_i8(af2, bf0, acc[mi0 + 2][ni0 + 0], 0, 0, 0);
      acc[mi0 + 3][ni0 + 0] = __builtin_amdgcn_mfma_i32_16x16x64_i8(af3, bf0, acc[mi0 + 3][ni0 + 0], 0, 0, 0);
      acc[mi0 + 0][ni0 + 1] = __builtin_amdgcn_mfma_i32_16x16x64_i8(af0, bf1, acc[mi0 + 0][ni0 + 1], 0, 0, 0);
      acc[mi0 + 1][ni0 + 1] = __builtin_amdgcn_mfma_i32_16x16x64_i8(af1, bf1, acc[mi0 + 1][ni0 + 1], 0, 0, 0);
      acc[mi0 + 2][ni0 + 1] = __builtin_amdgcn_mfma_i32_16x16x64_i8(af2, bf1, acc[mi0 + 2][ni0 + 1], 0, 0, 0);
      acc[mi0 + 3][ni0 + 1] = __builtin_amdgcn_mfma_i32_16x16x64_i8(af3, bf1, acc[mi0 + 3][ni0 + 1], 0, 0, 0);
      __builtin_amdgcn_s_setprio(0);

      if (q == 3) {
        // once per K-tile: ensure tile t+1 landed; keep t+2/t+3 in flight
        if (t < NT - 3)       WAITV(8);
        else if (t == NT - 3) WAITV(4);
        else if (t == NT - 2) WAITV(0);
        // t == NT-1: nothing outstanding
      }
      BAR();
    }

    bufo += BUFB;  if (bufo == NBUF * BUFB) bufo = 0;
    sbufo += BUFB; if (sbufo == NBUF * BUFB) sbufo = 0;
  }

  // epilogue: dequant + bias + weight_scale
  const float wsc = wscale_p[0];
  const int rbase = (lane >> 4) * 4;
  float bv[4];
#pragma unroll
  for (int ni = 0; ni < 4; ++ni) bv[ni] = bias[n0 + wc * 64 + ni * 16 + fr];
#pragma unroll
  for (int mi = 0; mi < 8; ++mi) {
#pragma unroll
    for (int r = 0; r < 4; ++r) {
      const int m = m0 + wr * 128 + mi * 16 + rbase + r;
      const float ds = dscale[m];
      float* orow = out + (size_t)m * OUT_F + n0 + wc * 64;
#pragma unroll
      for (int ni = 0; ni < 4; ++ni) {
        orow[ni * 16 + fr] = ((float)acc[mi][ni][r] * ds + bv[ni]) * wsc;
      }
    }
  }
#undef STAGE_ALL
}

extern "C" void kernel_launch(void* const* d_in, const int* in_sizes, int n_in,
                              void* d_out, int out_size, void* d_ws, size_t ws_size,
                              hipStream_t stream) {
  const float* x = (const float*)d_in[0];
  const float* W = (const float*)d_in[1];
  const float* rmsw = (const float*)d_in[2];
  const float* bias = (const float*)d_in[3];
  const float* wscale = (const float*)d_in[4];
  float* out = (float*)d_out;

  signed char* q = (signed char*)d_ws;                     // 32 MB
  signed char* Wq = q + (size_t)NTOK * IN_F;               // 16 MB
  float* dscale = (float*)(Wq + (size_t)OUT_F * IN_F);     // 32 KB

  rmsq_kernel<<<NTOK, 256, 0, stream>>>(x, rmsw, q, dscale);
  wconv_kernel<<<(OUT_F * IN_F / 4) / 256, 256, 0, stream>>>(W, Wq);
  gemm_kernel<<<(NTOK / BM) * (OUT_F / BN), 512, 0, stream>>>(q, Wq, dscale,
                                                              bias, wscale, out);
}

// Round 5
// 196.535 us; speedup vs baseline: 1.0616x; 1.0616x over previous
//
#include <hip/hip_runtime.h>

#define IN_F 4096
#define OUT_F 4096
#define NTOK 8192   // B*S = 4*2048
#define KDIM 4096

using i32x4 = __attribute__((ext_vector_type(4))) int;
using f32x4 = __attribute__((ext_vector_type(4))) float;

__device__ __forceinline__ void gload_lds16(const void* g, void* l) {
  __builtin_amdgcn_global_load_lds(
      (const __attribute__((address_space(1))) void*)g,
      (__attribute__((address_space(3))) void*)l, 16, 0, 0);
}

#define WAITV(n) asm volatile("s_waitcnt vmcnt(" #n ")" ::: "memory")
#define BAR() do { asm volatile("" ::: "memory"); __builtin_amdgcn_s_barrier(); \
                   asm volatile("" ::: "memory"); } while (0)

// ---------------- Pass 1: RMSNorm + per-token int8 absmax quant ------------
__global__ __launch_bounds__(256) void rmsq_kernel(
    const float* __restrict__ x, const float* __restrict__ rmsw,
    signed char* __restrict__ q, float* __restrict__ dscale) {
  const int tok = blockIdx.x;
  const int tid = threadIdx.x;
  const f32x4* xr = (const f32x4*)(x + (size_t)tok * IN_F);
  const f32x4* wr = (const f32x4*)rmsw;

  f32x4 v[4];
  float ss = 0.f;
#pragma unroll
  for (int c = 0; c < 4; ++c) {
    v[c] = xr[c * 256 + tid];
    ss += v[c].x * v[c].x + v[c].y * v[c].y + v[c].z * v[c].z + v[c].w * v[c].w;
  }

  __shared__ float red[4];
#pragma unroll
  for (int off = 32; off > 0; off >>= 1) ss += __shfl_down(ss, off, 64);
  const int wid = tid >> 6;
  if ((tid & 63) == 0) red[wid] = ss;
  __syncthreads();
  const float tot = red[0] + red[1] + red[2] + red[3];
  const float rinv = rsqrtf(tot * (1.0f / IN_F) + 1e-6f);

  f32x4 h[4];
  float amax = 0.f;
#pragma unroll
  for (int c = 0; c < 4; ++c) {
    f32x4 w = wr[c * 256 + tid];
    h[c].x = v[c].x * rinv * w.x;
    h[c].y = v[c].y * rinv * w.y;
    h[c].z = v[c].z * rinv * w.z;
    h[c].w = v[c].w * rinv * w.w;
    amax = fmaxf(amax, fabsf(h[c].x));
    amax = fmaxf(amax, fabsf(h[c].y));
    amax = fmaxf(amax, fabsf(h[c].z));
    amax = fmaxf(amax, fabsf(h[c].w));
  }

  __syncthreads();
#pragma unroll
  for (int off = 32; off > 0; off >>= 1)
    amax = fmaxf(amax, __shfl_down(amax, off, 64));
  if ((tid & 63) == 0) red[wid] = amax;
  __syncthreads();
  amax = fmaxf(fmaxf(red[0], red[1]), fmaxf(red[2], red[3]));
  amax = fmaxf(amax, 1e-5f);
  const float qs = 127.0f / amax;
  if (tid == 0) dscale[tok] = amax * (1.0f / 127.0f);

  uint* qo = (uint*)(q + (size_t)tok * IN_F);
#pragma unroll
  for (int c = 0; c < 4; ++c) {
    float r0 = fminf(fmaxf(rintf(h[c].x * qs), -128.f), 127.f);
    float r1 = fminf(fmaxf(rintf(h[c].y * qs), -128.f), 127.f);
    float r2 = fminf(fmaxf(rintf(h[c].z * qs), -128.f), 127.f);
    float r3 = fminf(fmaxf(rintf(h[c].w * qs), -128.f), 127.f);
    uint p = ((uint)((int)r0 & 255)) | ((uint)((int)r1 & 255) << 8) |
             ((uint)((int)r2 & 255) << 16) | ((uint)((int)r3 & 255) << 24);
    qo[c * 256 + tid] = p;
  }
}

// ---------------- Pass 2: W float32 {-1,0,1} -> int8 ----------------------
__global__ __launch_bounds__(256) void wconv_kernel(
    const float* __restrict__ W, signed char* __restrict__ Wq) {
  const int idx = blockIdx.x * 256 + threadIdx.x;
  f32x4 w = ((const f32x4*)W)[idx];
  uint p = ((uint)((int)w.x & 255)) | ((uint)((int)w.y & 255) << 8) |
           ((uint)((int)w.z & 255) << 16) | ((uint)((int)w.w & 255) << 24);
  ((uint*)Wq)[idx] = p;
}

// ---------------- Pass 3: software-pipelined 4-phase int8 GEMM -------------
// 256x256 tile, BK=64, 8 waves (2Mx4N). Phase q: {barrier | ds_read quadrant
// q+1 | 1 stage chunk | lgkmcnt(6) | setprio 8xMFMA on quadrant q}.
// Fragments read one phase AHEAD of consumption (ILP). Counted vmcnt(7)
// at tile boundary only. 4 LDS buffers, depth-3 prefetch.
#define BM 256
#define BN 256
#define BK 64
#define NT (KDIM / BK)      // 64 K-tiles
#define TILEB (BM * BK)     // 16 KB
#define BUFB (2 * TILEB)    // 32 KB per buffer (A + B)
#define NBUF 4
#define LDSMASK (NBUF * BUFB - 1)   // 131072 - 1

__global__ __launch_bounds__(512, 2) void gemm_kernel(
    const signed char* __restrict__ A, const signed char* __restrict__ Bw,
    const float* __restrict__ dscale, const float* __restrict__ bias,
    const float* __restrict__ wscale_p, float* __restrict__ out) {
  __shared__ __align__(16) signed char lds[NBUF * BUFB];  // 128 KB

  const int tid = threadIdx.x;
  const int lane = tid & 63;
  const int wid = tid >> 6;
  const int wr = wid >> 2;  // 0..1 : 128 output rows
  const int wc = wid & 3;   // 0..3 : 64 output cols

  // XCD-aware bijective swizzle (512 blocks, 512%8==0)
  const int bid = blockIdx.x;
  const int swz = (bid & 7) * 64 + (bid >> 3);
  const int m0 = (swz & 31) * BM;
  const int n0 = (swz >> 5) * BN;

  // staging: chunk c -> row r=c>>2, physical slot p=c&3 holds logical slot
  // s = p ^ ((r>>1)&3)  (pre-swizzled global source, linear LDS dest)
  const int cA0 = tid, cA1 = tid + 512;
  const int rA0 = cA0 >> 2, rA1 = cA1 >> 2;
  const int sA0 = (cA0 & 3) ^ ((rA0 >> 1) & 3);
  const int sA1 = (cA1 & 3) ^ ((rA1 >> 1) & 3);
  const signed char* agp0 = A + (size_t)(m0 + rA0) * KDIM + sA0 * 16;
  const signed char* agp1 = A + (size_t)(m0 + rA1) * KDIM + sA1 * 16;
  const signed char* bgp0 = Bw + (size_t)(n0 + rA0) * KDIM + sA0 * 16;
  const signed char* bgp1 = Bw + (size_t)(n0 + rA1) * KDIM + sA1 * 16;

#define STAGE_ALL(kt, bufoff)                                              \
  do {                                                                     \
    const int k0_ = (kt) * BK;                                             \
    signed char* lb_ = &lds[(bufoff)];                                     \
    gload_lds16(agp0 + k0_, lb_ + cA0 * 16);                               \
    gload_lds16(agp1 + k0_, lb_ + cA1 * 16);                               \
    gload_lds16(bgp0 + k0_, lb_ + TILEB + cA0 * 16);                       \
    gload_lds16(bgp1 + k0_, lb_ + TILEB + cA1 * 16);                       \
  } while (0)

  // fragment read offsets (swizzled, loop-invariant)
  const int fr = lane & 15;
  const int ks = lane >> 4;
  int offA[8], offB[4];
#pragma unroll
  for (int mi = 0; mi < 8; ++mi) {
    const int row = wr * 128 + mi * 16 + fr;
    offA[mi] = row * BK + ((ks ^ ((row >> 1) & 3)) * 16);
  }
#pragma unroll
  for (int ni = 0; ni < 4; ++ni) {
    const int row = wc * 64 + ni * 16 + fr;
    offB[ni] = TILEB + row * BK + ((ks ^ ((row >> 1) & 3)) * 16);
  }

  i32x4 acc[8][4];
#pragma unroll
  for (int i = 0; i < 8; ++i)
#pragma unroll
    for (int j = 0; j < 4; ++j) acc[i][j] = (i32x4){0, 0, 0, 0};

  // prologue: depth-3 fill, guard tile 0, pre-read quadrant 0 of tile 0
  STAGE_ALL(0, 0);
  STAGE_ALL(1, BUFB);
  STAGE_ALL(2, 2 * BUFB);
  WAITV(8);
  BAR();
  i32x4 a0 = *(const i32x4*)(lds + offA[0]);
  i32x4 a1 = *(const i32x4*)(lds + offA[1]);
  i32x4 a2 = *(const i32x4*)(lds + offA[2]);
  i32x4 a3 = *(const i32x4*)(lds + offA[3]);
  i32x4 b0v = *(const i32x4*)(lds + offB[0]);
  i32x4 b1v = *(const i32x4*)(lds + offB[1]);

  int bufo = 0;
  for (int t = 0; t < NT; ++t) {
    const signed char* bp = &lds[bufo];
    const signed char* np = (t + 1 < NT) ? &lds[(bufo + BUFB) & LDSMASK] : bp;
    signed char* sb = &lds[(bufo + 3 * BUFB) & LDSMASK];
    const int k3 = (t + 3) * BK;
    const bool more = (t + 3 < NT);

#pragma unroll
    for (int q = 0; q < 4; ++q) {
      const int mi0 = (q >> 1) * 4, ni0 = (q & 1) * 2;
      const int qn = (q + 1) & 3;
      const int mi0n = (qn >> 1) * 4, ni0n = (qn & 1) * 2;
      const signed char* rp = (q < 3) ? bp : np;

      // [A] tile-boundary residency guard (before the barrier)
      if (q == 3) {
        if (t < NT - 3)       WAITV(7);
        else if (t == NT - 3) WAITV(4);
        else if (t == NT - 2) WAITV(0);
      }
      // [B] one barrier per phase
      BAR();

      // [C] read NEXT quadrant's fragments (consumed next phase)
      i32x4 na0 = *(const i32x4*)(rp + offA[mi0n + 0]);
      i32x4 na1 = *(const i32x4*)(rp + offA[mi0n + 1]);
      i32x4 na2 = *(const i32x4*)(rp + offA[mi0n + 2]);
      i32x4 na3 = *(const i32x4*)(rp + offA[mi0n + 3]);
      i32x4 nb0 = *(const i32x4*)(rp + offB[ni0n + 0]);
      i32x4 nb1 = *(const i32x4*)(rp + offB[ni0n + 1]);

      // [D] issue one staging chunk of tile t+3
      if (more) {
        if (q == 0)      gload_lds16(agp0 + k3, sb + cA0 * 16);
        else if (q == 1) gload_lds16(agp1 + k3, sb + cA1 * 16);
        else if (q == 2) gload_lds16(bgp0 + k3, sb + TILEB + cA0 * 16);
        else             gload_lds16(bgp1 + k3, sb + TILEB + cA1 * 16);
      }

      // [E] previous phase's 6 reads complete (6 newer outstanding)
      asm volatile("s_waitcnt lgkmcnt(6)" ::: "memory");

      // [F] MFMA on CURRENT quadrant (fragments read last phase)
      __builtin_amdgcn_s_setprio(1);
      acc[mi0 + 0][ni0 + 0] = __builtin_amdgcn_mfma_i32_16x16x64_i8(a0, b0v, acc[mi0 + 0][ni0 + 0], 0, 0, 0);
      acc[mi0 + 1][ni0 + 0] = __builtin_amdgcn_mfma_i32_16x16x64_i8(a1, b0v, acc[mi0 + 1][ni0 + 0], 0, 0, 0);
      acc[mi0 + 2][ni0 + 0] = __builtin_amdgcn_mfma_i32_16x16x64_i8(a2, b0v, acc[mi0 + 2][ni0 + 0], 0, 0, 0);
      acc[mi0 + 3][ni0 + 0] = __builtin_amdgcn_mfma_i32_16x16x64_i8(a3, b0v, acc[mi0 + 3][ni0 + 0], 0, 0, 0);
      acc[mi0 + 0][ni0 + 1] = __builtin_amdgcn_mfma_i32_16x16x64_i8(a0, b1v, acc[mi0 + 0][ni0 + 1], 0, 0, 0);
      acc[mi0 + 1][ni0 + 1] = __builtin_amdgcn_mfma_i32_16x16x64_i8(a1, b1v, acc[mi0 + 1][ni0 + 1], 0, 0, 0);
      acc[mi0 + 2][ni0 + 1] = __builtin_amdgcn_mfma_i32_16x16x64_i8(a2, b1v, acc[mi0 + 2][ni0 + 1], 0, 0, 0);
      acc[mi0 + 3][ni0 + 1] = __builtin_amdgcn_mfma_i32_16x16x64_i8(a3, b1v, acc[mi0 + 3][ni0 + 1], 0, 0, 0);
      __builtin_amdgcn_s_setprio(0);

      // rotate prefetch registers
      a0 = na0; a1 = na1; a2 = na2; a3 = na3; b0v = nb0; b1v = nb1;
    }

    bufo = (bufo + BUFB) & LDSMASK;
  }

  // epilogue: dequant + bias + weight_scale
  const float wsc = wscale_p[0];
  const int rbase = (lane >> 4) * 4;
  float bv[4];
#pragma unroll
  for (int ni = 0; ni < 4; ++ni) bv[ni] = bias[n0 + wc * 64 + ni * 16 + fr];
#pragma unroll
  for (int mi = 0; mi < 8; ++mi) {
#pragma unroll
    for (int r = 0; r < 4; ++r) {
      const int m = m0 + wr * 128 + mi * 16 + rbase + r;
      const float ds = dscale[m];
      float* orow = out + (size_t)m * OUT_F + n0 + wc * 64;
#pragma unroll
      for (int ni = 0; ni < 4; ++ni) {
        orow[ni * 16 + fr] = ((float)acc[mi][ni][r] * ds + bv[ni]) * wsc;
      }
    }
  }
#undef STAGE_ALL
}

extern "C" void kernel_launch(void* const* d_in, const int* in_sizes, int n_in,
                              void* d_out, int out_size, void* d_ws, size_t ws_size,
                              hipStream_t stream) {
  const float* x = (const float*)d_in[0];
  const float* W = (const float*)d_in[1];
  const float* rmsw = (const float*)d_in[2];
  const float* bias = (const float*)d_in[3];
  const float* wscale = (const float*)d_in[4];
  float* out = (float*)d_out;

  signed char* q = (signed char*)d_ws;                     // 32 MB
  signed char* Wq = q + (size_t)NTOK * IN_F;               // 16 MB
  float* dscale = (float*)(Wq + (size_t)OUT_F * IN_F);     // 32 KB

  rmsq_kernel<<<NTOK, 256, 0, stream>>>(x, rmsw, q, dscale);
  wconv_kernel<<<(OUT_F * IN_F / 4) / 256, 256, 0, stream>>>(W, Wq);
  gemm_kernel<<<(NTOK / BM) * (OUT_F / BN), 512, 0, stream>>>(q, Wq, dscale,
                                                              bias, wscale, out);
}

// Round 6
// 192.012 us; speedup vs baseline: 1.0866x; 1.0236x over previous
//
#include <hip/hip_runtime.h>

#define IN_F 4096
#define OUT_F 4096
#define NTOK 8192   // B*S = 4*2048
#define KDIM 4096

using i32x4 = __attribute__((ext_vector_type(4))) int;
using f32x4 = __attribute__((ext_vector_type(4))) float;

__device__ __forceinline__ void gload_lds16(const void* g, void* l) {
  __builtin_amdgcn_global_load_lds(
      (const __attribute__((address_space(1))) void*)g,
      (__attribute__((address_space(3))) void*)l, 16, 0, 0);
}

#define WAITV(n) asm volatile("s_waitcnt vmcnt(" #n ")" ::: "memory")
#define BAR() do { asm volatile("" ::: "memory"); __builtin_amdgcn_s_barrier(); \
                   asm volatile("" ::: "memory"); } while (0)

// ---------------- Pass 1: RMSNorm + per-token int8 absmax quant ------------
__global__ __launch_bounds__(256) void rmsq_kernel(
    const float* __restrict__ x, const float* __restrict__ rmsw,
    signed char* __restrict__ q, float* __restrict__ dscale) {
  const int tok = blockIdx.x;
  const int tid = threadIdx.x;
  const f32x4* xr = (const f32x4*)(x + (size_t)tok * IN_F);
  const f32x4* wr = (const f32x4*)rmsw;

  f32x4 v[4];
  float ss = 0.f;
#pragma unroll
  for (int c = 0; c < 4; ++c) {
    v[c] = xr[c * 256 + tid];
    ss += v[c].x * v[c].x + v[c].y * v[c].y + v[c].z * v[c].z + v[c].w * v[c].w;
  }

  __shared__ float red[4];
#pragma unroll
  for (int off = 32; off > 0; off >>= 1) ss += __shfl_down(ss, off, 64);
  const int wid = tid >> 6;
  if ((tid & 63) == 0) red[wid] = ss;
  __syncthreads();
  const float tot = red[0] + red[1] + red[2] + red[3];
  const float rinv = rsqrtf(tot * (1.0f / IN_F) + 1e-6f);

  f32x4 h[4];
  float amax = 0.f;
#pragma unroll
  for (int c = 0; c < 4; ++c) {
    f32x4 w = wr[c * 256 + tid];
    h[c].x = v[c].x * rinv * w.x;
    h[c].y = v[c].y * rinv * w.y;
    h[c].z = v[c].z * rinv * w.z;
    h[c].w = v[c].w * rinv * w.w;
    amax = fmaxf(amax, fabsf(h[c].x));
    amax = fmaxf(amax, fabsf(h[c].y));
    amax = fmaxf(amax, fabsf(h[c].z));
    amax = fmaxf(amax, fabsf(h[c].w));
  }

  __syncthreads();
#pragma unroll
  for (int off = 32; off > 0; off >>= 1)
    amax = fmaxf(amax, __shfl_down(amax, off, 64));
  if ((tid & 63) == 0) red[wid] = amax;
  __syncthreads();
  amax = fmaxf(fmaxf(red[0], red[1]), fmaxf(red[2], red[3]));
  amax = fmaxf(amax, 1e-5f);
  const float qs = 127.0f / amax;
  if (tid == 0) dscale[tok] = amax * (1.0f / 127.0f);

  uint* qo = (uint*)(q + (size_t)tok * IN_F);
#pragma unroll
  for (int c = 0; c < 4; ++c) {
    float r0 = fminf(fmaxf(rintf(h[c].x * qs), -128.f), 127.f);
    float r1 = fminf(fmaxf(rintf(h[c].y * qs), -128.f), 127.f);
    float r2 = fminf(fmaxf(rintf(h[c].z * qs), -128.f), 127.f);
    float r3 = fminf(fmaxf(rintf(h[c].w * qs), -128.f), 127.f);
    uint p = ((uint)((int)r0 & 255)) | ((uint)((int)r1 & 255) << 8) |
             ((uint)((int)r2 & 255) << 16) | ((uint)((int)r3 & 255) << 24);
    qo[c * 256 + tid] = p;
  }
}

// ---------------- Pass 2: W float32 {-1,0,1} -> int8 ----------------------
__global__ __launch_bounds__(256) void wconv_kernel(
    const float* __restrict__ W, signed char* __restrict__ Wq) {
  const int idx = blockIdx.x * 256 + threadIdx.x;
  f32x4 w = ((const f32x4*)W)[idx];
  uint p = ((uint)((int)w.x & 255)) | ((uint)((int)w.y & 255) << 8) |
           ((uint)((int)w.z & 255) << 16) | ((uint)((int)w.w & 255) << 24);
  ((uint*)Wq)[idx] = p;
}

// ---------------- Pass 3: int8 GEMM, 2 blocks/CU ---------------------------
// 128x256 tile, BK=64, 4 waves (1Mx4N, per-wave 128x64 out). 3 LDS buffers
// (24 KB each, 72 KB total -> 2 blocks/CU on 160 KB LDS). Depth-2 prefetch,
// counted vmcnt(6), ONE barrier per tile. Two independent blocks per CU
// decouple barrier stalls (latency-bound fix: fill MFMA pipe via TLP).
#define BM 128
#define BN 256
#define BK 64
#define NT (KDIM / BK)       // 64 K-tiles
#define ATILEB (BM * BK)     // 8192
#define BTILEB (BN * BK)     // 16384
#define BUFB (ATILEB + BTILEB)  // 24576
#define NBUF 3

__global__ __launch_bounds__(256, 2) void gemm_kernel(
    const signed char* __restrict__ A, const signed char* __restrict__ Bw,
    const float* __restrict__ dscale, const float* __restrict__ bias,
    const float* __restrict__ wscale_p, float* __restrict__ out) {
  __shared__ __align__(16) signed char lds[NBUF * BUFB];  // 72 KB

  const int tid = threadIdx.x;
  const int lane = tid & 63;
  const int wc = tid >> 6;   // 0..3 : 64 output cols each

  // XCD-aware bijective swizzle (1024 blocks, 1024%8==0). Consecutive swz on
  // one XCD share the B-panel (n0) -> W stays L2-resident per XCD.
  const int bid = blockIdx.x;
  const int swz = (bid & 7) * 128 + (bid >> 3);
  const int m0 = (swz & 63) * BM;
  const int n0 = (swz >> 6) * BN;

  // staging: chunk c -> row r=c>>2, phys slot p=c&3 holds logical slot
  // s = p ^ ((r>>1)&3)  (pre-swizzled global source, linear LDS dest)
  const int cA0 = tid, cA1 = tid + 256;          // A: 512 chunks
  const int rA0 = cA0 >> 2, rA1 = cA1 >> 2;
  const int sA0 = (cA0 & 3) ^ ((rA0 >> 1) & 3);
  const int sA1 = (cA1 & 3) ^ ((rA1 >> 1) & 3);
  const signed char* agp0 = A + (size_t)(m0 + rA0) * KDIM + sA0 * 16;
  const signed char* agp1 = A + (size_t)(m0 + rA1) * KDIM + sA1 * 16;
  // B: 1024 chunks, rows 0..255
  const int rB = tid >> 2;
  const signed char* bgp[4];
#pragma unroll
  for (int j = 0; j < 4; ++j) {
    const int rBj = rB + j * 64;
    const int sBj = (tid & 3) ^ ((rBj >> 1) & 3);
    bgp[j] = Bw + (size_t)(n0 + rBj) * KDIM + sBj * 16;
  }

#define STAGE(kt, boff)                                                    \
  do {                                                                     \
    const int k0_ = (kt) * BK;                                             \
    signed char* lb_ = &lds[(boff)];                                       \
    gload_lds16(agp0 + k0_, lb_ + cA0 * 16);                               \
    gload_lds16(agp1 + k0_, lb_ + cA1 * 16);                               \
    gload_lds16(bgp[0] + k0_, lb_ + ATILEB + (tid + 0 * 256) * 16);        \
    gload_lds16(bgp[1] + k0_, lb_ + ATILEB + (tid + 1 * 256) * 16);        \
    gload_lds16(bgp[2] + k0_, lb_ + ATILEB + (tid + 2 * 256) * 16);        \
    gload_lds16(bgp[3] + k0_, lb_ + ATILEB + (tid + 3 * 256) * 16);        \
  } while (0)

  // fragment read offsets (swizzled, loop-invariant)
  const int fr = lane & 15;
  const int ks = lane >> 4;
  int offA[8], offB[4];
#pragma unroll
  for (int mi = 0; mi < 8; ++mi) {
    const int row = mi * 16 + fr;
    offA[mi] = row * BK + ((ks ^ ((row >> 1) & 3)) * 16);
  }
#pragma unroll
  for (int ni = 0; ni < 4; ++ni) {
    const int row = wc * 64 + ni * 16 + fr;
    offB[ni] = ATILEB + row * BK + ((ks ^ ((row >> 1) & 3)) * 16);
  }

  i32x4 acc[8][4];
#pragma unroll
  for (int i = 0; i < 8; ++i)
#pragma unroll
    for (int j = 0; j < 4; ++j) acc[i][j] = (i32x4){0, 0, 0, 0};

  // prologue: depth-2 fill (12 outstanding; tile-0 guard is loop's WAITV(6))
  STAGE(0, 0);
  STAGE(1, BUFB);

  int br = 0;             // buffer holding tile t
  int bs = 2 * BUFB;      // buffer to stage tile t+2 into
  for (int t = 0; t < NT; ++t) {
    // own tile-t chunks drained; BAR -> everyone's chunks visible, and
    // everyone finished reading buf[(t-1)%3] (the stage target below)
    if (t < NT - 1) WAITV(6); else WAITV(0);
    BAR();

    const signed char* bp = &lds[br];
    i32x4 af[8], bf[4];
#pragma unroll
    for (int mi = 0; mi < 8; ++mi) af[mi] = *(const i32x4*)(bp + offA[mi]);
#pragma unroll
    for (int ni = 0; ni < 4; ++ni) bf[ni] = *(const i32x4*)(bp + offB[ni]);

    if (t + 2 < NT) STAGE(t + 2, bs);

    __builtin_amdgcn_s_setprio(1);
#pragma unroll
    for (int mi = 0; mi < 8; ++mi)
#pragma unroll
      for (int ni = 0; ni < 4; ++ni)
        acc[mi][ni] = __builtin_amdgcn_mfma_i32_16x16x64_i8(af[mi], bf[ni],
                                                            acc[mi][ni], 0, 0, 0);
    __builtin_amdgcn_s_setprio(0);

    br += BUFB; if (br == NBUF * BUFB) br = 0;
    bs += BUFB; if (bs == NBUF * BUFB) bs = 0;
  }

  // epilogue: dequant + bias + weight_scale
  const float wsc = wscale_p[0];
  const int rbase = (lane >> 4) * 4;
  float bv[4];
#pragma unroll
  for (int ni = 0; ni < 4; ++ni) bv[ni] = bias[n0 + wc * 64 + ni * 16 + fr];
#pragma unroll
  for (int mi = 0; mi < 8; ++mi) {
#pragma unroll
    for (int r = 0; r < 4; ++r) {
      const int m = m0 + mi * 16 + rbase + r;
      const float ds = dscale[m];
      float* orow = out + (size_t)m * OUT_F + n0 + wc * 64;
#pragma unroll
      for (int ni = 0; ni < 4; ++ni) {
        orow[ni * 16 + fr] = ((float)acc[mi][ni][r] * ds + bv[ni]) * wsc;
      }
    }
  }
#undef STAGE
}

extern "C" void kernel_launch(void* const* d_in, const int* in_sizes, int n_in,
                              void* d_out, int out_size, void* d_ws, size_t ws_size,
                              hipStream_t stream) {
  const float* x = (const float*)d_in[0];
  const float* W = (const float*)d_in[1];
  const float* rmsw = (const float*)d_in[2];
  const float* bias = (const float*)d_in[3];
  const float* wscale = (const float*)d_in[4];
  float* out = (float*)d_out;

  signed char* q = (signed char*)d_ws;                     // 32 MB
  signed char* Wq = q + (size_t)NTOK * IN_F;               // 16 MB
  float* dscale = (float*)(Wq + (size_t)OUT_F * IN_F);     // 32 KB

  rmsq_kernel<<<NTOK, 256, 0, stream>>>(x, rmsw, q, dscale);
  wconv_kernel<<<(OUT_F * IN_F / 4) / 256, 256, 0, stream>>>(W, Wq);
  gemm_kernel<<<(NTOK / BM) * (OUT_F / BN), 256, 0, stream>>>(q, Wq, dscale,
                                                              bias, wscale, out);
}